// Round 8
// baseline (26.770 us; speedup 1.0000x reference)
//
#include <hip/hip_runtime.h>

// BinancePerpStructuralLoss — dense-mapped streaming stencil.
// Chunk = 16 rows = 960 float4 = 15 dense aligned 1024B wave-loads (100% lane use).
// Signs depend only on f4idx % 5  (m: 0..4 -> g0 = 4m within a 20-col group):
//   m=0: (+,+,+,+) spread   m=1: (+,+,+,+)   m=2: (+,0,-,-)   m=3: (-,-,-,-)
//   m=4: (-,-,-,0)
// All pairs crossing a 64-lane step land on g=19 (unconstrained) except
// lane63 nx (j<=3, from v[k+1].x lane0) and the two spread zz fixes
// (j==2: lane62 <- v[k+1].z lane0;  j==3: lane63 <- v[k+1].z lane1).
// Two-kernel reduction: per-block partials -> d_ws, single-wave finisher.

#define FEAT 240
#define CHUNK_ROWS 16
#define F4_PER_CHUNK 960
#define K_STEPS 15
#define NTHREADS 256
#define WAVES_PER_BLOCK 4
#define CHUNKS_PER_WAVE 2
#define BATCH_INV (1.0f / 128.0f)

typedef float vfloat4 __attribute__((ext_vector_type(4)));

__device__ __forceinline__ float sgn_of_g(int g) {
    if (g <= 8) return 1.0f;                 // bid monotonicity
    if (g >= 10 && g <= 18) return -1.0f;    // ask monotonicity
    return 0.0f;                             // g==9,19: no constraint
}

__device__ __forceinline__ vfloat4 nt_load4(const float* p) {
    return __builtin_nontemporal_load(reinterpret_cast<const vfloat4*>(p));
}

template <bool ATOMIC>
__global__ __launch_bounds__(NTHREADS)
void bpsl_main(const float* __restrict__ pred, int n_rows, float* __restrict__ dst)
{
    const int tid  = threadIdx.x;
    const int lane = tid & 63;
    const int widx = tid >> 6;
    const int gw   = blockIdx.x * WAVES_PER_BLOCK + widx;

    const int n_chunks = n_rows / CHUNK_ROWS;

    // Per-lane sign tables for j = k % 5:  m = (lane - j) mod 5, g0 = 4m.
    float S0[5], S1[5], S2[5], S3[5], SP[5];
    #pragma unroll
    for (int j = 0; j < 5; ++j) {
        int m = (lane - j) % 5; if (m < 0) m += 5;
        const int g0 = m * 4;
        S0[j] = sgn_of_g(g0 + 0);
        S1[j] = sgn_of_g(g0 + 1);
        S2[j] = sgn_of_g(g0 + 2);
        S3[j] = sgn_of_g(g0 + 3);
        SP[j] = (m == 0) ? 1.0f : 0.0f;
    }

    float acc = 0.0f;

    const int ch0 = gw * CHUNKS_PER_WAVE;
    #pragma unroll
    for (int cc = 0; cc < CHUNKS_PER_WAVE; ++cc) {
        const int ch = ch0 + cc;
        if (ch >= n_chunks) break;

        const float* __restrict__ base =
            pred + (size_t)ch * (F4_PER_CHUNK * 4) + lane * 4;

        vfloat4 v[K_STEPS];
        #pragma unroll
        for (int k = 0; k < K_STEPS; ++k)
            v[k] = nt_load4(base + k * 256);          // dense aligned 1024B/step

        #pragma unroll
        for (int k = 0; k < K_STEPS; ++k) {
            const int j = k % 5;                       // compile-time
            float nx = __shfl_down(v[k].x, 1, 64);
            float zz = __shfl_down(v[k].z, 2, 64);
            if (j <= 3) {                              // implies k <= 13
                const float fx = __shfl(v[k + 1].x, 0, 64);
                nx = (lane == 63) ? fx : nx;
            }
            if (j == 2) {
                const float fz = __shfl(v[k + 1].z, 0, 64);
                zz = (lane == 62) ? fz : zz;
            }
            if (j == 3) {
                const float fz = __shfl(v[k + 1].z, 1, 64);
                zz = (lane == 63) ? fz : zz;
            }
            acc += fmaxf(S0[j] * (v[k].y - v[k].x), 0.f)
                 + fmaxf(S1[j] * (v[k].z - v[k].y), 0.f)
                 + fmaxf(S2[j] * (v[k].w - v[k].z), 0.f)
                 + fmaxf(S3[j] * (nx     - v[k].w), 0.f)
                 + fmaxf(SP[j] * (v[k].x - zz    ), 0.f);
        }
    }

    // Leftover rows (n_rows % 16 != 0; never in practice): wave 0, per-row map.
    if (gw == 0) {
        for (int r = n_chunks * CHUNK_ROWS; r < n_rows; ++r) {
            const int lc = lane < 60 ? lane : 59;      // clamped loads
            vfloat4 v = nt_load4(pred + (size_t)r * FEAT + lc * 4);
            float nx = __shfl_down(v.x, 1, 64);
            float zz = __shfl_down(v.z, 2, 64);
            // per-row mapping == j=0 tables (m = lane % 5)
            float t = fmaxf(S0[0] * (v.y - v.x), 0.f)
                    + fmaxf(S1[0] * (v.z - v.y), 0.f)
                    + fmaxf(S2[0] * (v.w - v.z), 0.f)
                    + fmaxf(S3[0] * (nx  - v.w), 0.f)
                    + fmaxf(SP[0] * (v.x - zz ), 0.f);
            if (lane < 60) acc += t;
        }
    }

    // wave reduce -> block reduce -> one write (or atomic fallback) per block
    #pragma unroll
    for (int off = 32; off > 0; off >>= 1)
        acc += __shfl_down(acc, off, 64);

    __shared__ float wsum[WAVES_PER_BLOCK];
    if ((tid & 63) == 0) wsum[widx] = acc;
    __syncthreads();
    if (tid == 0) {
        float bs = wsum[0];
        #pragma unroll
        for (int w = 1; w < WAVES_PER_BLOCK; ++w) bs += wsum[w];
        if (ATOMIC) atomicAdd(dst, bs * BATCH_INV);
        else        dst[blockIdx.x] = bs;
    }
}

// Single-wave finisher: n4 = grid/4 float4s; no LDS, no barrier.
__global__ __launch_bounds__(64)
void bpsl_finish(const float* __restrict__ ws, int n4, float* __restrict__ out)
{
    const int lane = threadIdx.x;
    const float4* w4 = reinterpret_cast<const float4*>(ws);
    float a = 0.0f;
    for (int i = lane; i < n4; i += 64) {
        float4 v = w4[i];
        a += (v.x + v.y) + (v.z + v.w);
    }
    #pragma unroll
    for (int off = 32; off > 0; off >>= 1)
        a += __shfl_down(a, off, 64);
    if (lane == 0) out[0] = a * BATCH_INV;
}

extern "C" void kernel_launch(void* const* d_in, const int* in_sizes, int n_in,
                              void* d_out, int out_size, void* d_ws, size_t ws_size,
                              hipStream_t stream)
{
    const float* pred = (const float*)d_in[0];
    float*       out  = (float*)d_out;
    float*       ws   = (float*)d_ws;

    const int n_rows   = in_sizes[0] / FEAT;                 // 131072
    const int n_chunks = n_rows / CHUNK_ROWS;                // 8192
    const int waves    = (n_chunks + CHUNKS_PER_WAVE - 1) / CHUNKS_PER_WAVE;
    const int grid     = (waves + WAVES_PER_BLOCK - 1) / WAVES_PER_BLOCK;  // 1024

    if (ws_size >= (size_t)grid * sizeof(float) && (grid % 4) == 0) {
        bpsl_main<false><<<grid, NTHREADS, 0, stream>>>(pred, n_rows, ws);
        bpsl_finish<<<1, 64, 0, stream>>>(ws, grid / 4, out);
    } else {
        (void)hipMemsetAsync(out, 0, sizeof(float), stream);
        bpsl_main<true><<<grid, NTHREADS, 0, stream>>>(pred, n_rows, out);
    }
}

// Round 9
// 26.134 us; speedup vs baseline: 1.0243x; 1.0243x over previous
//
#include <hip/hip_runtime.h>

// BinancePerpStructuralLoss as a streaming stencil (no gather, no LDS staging).
// Per 20-col group: pairs (g,g+1) with d = x[g+1]-x[g]:
//   g<=8 -> +d (bid mono), 10<=g<=18 -> -d (ask mono), g==9,19 -> unused.
//   spread: relu(x[0]-x[10]) per group.
// out = (1/128) * sum over all B*T rows.
// Two-kernel reduction: per-block partials -> d_ws, single-wave finisher.
// R3 lesson: no same-address atomic storms (~9ns each, serialized tail).
// R7 lesson: 60/64-lane mapping beats dense 64-lane remap (VGPR + shuffle cost).

#define FEAT 240
#define F4_PER_ROW 60
#define NTHREADS 256
#define WAVES_PER_BLOCK 4
#define ROWS_PER_WAVE 32
#define ROWS_PER_BLOCK (WAVES_PER_BLOCK * ROWS_PER_WAVE)   // 128
#define BATCH_INV (1.0f / 128.0f)

typedef float vfloat4 __attribute__((ext_vector_type(4)));  // native vec for nt builtin

__device__ __forceinline__ float pair_sign(int g, bool act) {
    if (!act) return 0.0f;
    if (g <= 8) return 1.0f;                 // bid monotonicity
    if (g >= 10 && g <= 18) return -1.0f;    // ask monotonicity
    return 0.0f;                             // g==9, g==19: no constraint
}

__device__ __forceinline__ float row_terms(vfloat4 v, float nx, float zz,
                                           float s0, float s1, float s2, float s3,
                                           float ssp)
{
    return fmaxf(s0 * (v.y - v.x), 0.f) + fmaxf(s1 * (v.z - v.y), 0.f)
         + fmaxf(s2 * (v.w - v.z), 0.f) + fmaxf(s3 * (nx - v.w), 0.f)
         + fmaxf(ssp * (v.x - zz), 0.f);
}

__device__ __forceinline__ vfloat4 nt_load4(const float* p) {
    // read-once stream: hint early eviction in L2/MALL
    return __builtin_nontemporal_load(reinterpret_cast<const vfloat4*>(p));
}

template <bool ATOMIC>
__global__ __launch_bounds__(NTHREADS)
void bpsl_main(const float* __restrict__ pred, int n_rows, float* __restrict__ dst)
{
    const int tid  = threadIdx.x;
    const int lane = tid & 63;
    const int widx = tid >> 6;
    const int gw   = blockIdx.x * WAVES_PER_BLOCK + widx;
    const int row0 = gw * ROWS_PER_WAVE;

    const bool act = lane < F4_PER_ROW;
    const int  lc  = act ? lane : (F4_PER_ROW - 1);   // clamped: loads always in-bounds
    const int  g0  = (lc * 4) % 20;                    // {0,4,8,12,16}

    const float s0  = pair_sign(g0 + 0, act);
    const float s1  = pair_sign(g0 + 1, act);
    const float s2  = pair_sign(g0 + 2, act);
    const float s3  = pair_sign(g0 + 3, act);
    const float ssp = (act && g0 == 0) ? 1.0f : 0.0f;  // spread lanes hold x[base+0]

    float acc = 0.0f;

    if (row0 < n_rows) {
        const float* __restrict__ p =
            pred + ((size_t)row0 * F4_PER_ROW + lc) * 4;
        const int rows = min(ROWS_PER_WAVE, n_rows - row0);

        int r = 0;
        #pragma unroll 1
        for (; r + 4 <= rows; r += 4) {
            // 4 independent loads in flight (contiguous rows -> linear stream)
            vfloat4 v0 = nt_load4(p + 0 * FEAT);
            vfloat4 v1 = nt_load4(p + 1 * FEAT);
            vfloat4 v2 = nt_load4(p + 2 * FEAT);
            vfloat4 v3 = nt_load4(p + 3 * FEAT);
            p += 4 * FEAT;

            float nx0 = __shfl_down(v0.x, 1, 64), z0 = __shfl_down(v0.z, 2, 64);
            float nx1 = __shfl_down(v1.x, 1, 64), z1 = __shfl_down(v1.z, 2, 64);
            float nx2 = __shfl_down(v2.x, 1, 64), z2 = __shfl_down(v2.z, 2, 64);
            float nx3 = __shfl_down(v3.x, 1, 64), z3 = __shfl_down(v3.z, 2, 64);

            acc += row_terms(v0, nx0, z0, s0, s1, s2, s3, ssp);
            acc += row_terms(v1, nx1, z1, s0, s1, s2, s3, ssp);
            acc += row_terms(v2, nx2, z2, s0, s1, s2, s3, ssp);
            acc += row_terms(v3, nx3, z3, s0, s1, s2, s3, ssp);
        }
        #pragma unroll 1
        for (; r < rows; ++r) {            // tail (unused at 131072 rows)
            vfloat4 v = nt_load4(p);
            p += FEAT;
            float nx = __shfl_down(v.x, 1, 64), zz = __shfl_down(v.z, 2, 64);
            acc += row_terms(v, nx, zz, s0, s1, s2, s3, ssp);
        }
    }

    // wave reduce -> block reduce -> one write (or atomic fallback) per block
    #pragma unroll
    for (int off = 32; off > 0; off >>= 1)
        acc += __shfl_down(acc, off, 64);

    __shared__ float wsum[WAVES_PER_BLOCK];
    if ((tid & 63) == 0) wsum[widx] = acc;
    __syncthreads();
    if (tid == 0) {
        float bs = wsum[0];
        #pragma unroll
        for (int w = 1; w < WAVES_PER_BLOCK; ++w) bs += wsum[w];
        if (ATOMIC) atomicAdd(dst, bs * BATCH_INV);
        else        dst[blockIdx.x] = bs;
    }
}

// Single-wave finisher: n4 = grid/4 float4s; no LDS, no barrier.
__global__ __launch_bounds__(64)
void bpsl_finish(const float* __restrict__ ws, int n4, float* __restrict__ out)
{
    const int lane = threadIdx.x;
    const float4* w4 = reinterpret_cast<const float4*>(ws);
    float a = 0.0f;
    for (int i = lane; i < n4; i += 64) {
        float4 v = w4[i];
        a += (v.x + v.y) + (v.z + v.w);
    }
    #pragma unroll
    for (int off = 32; off > 0; off >>= 1)
        a += __shfl_down(a, off, 64);
    if (lane == 0) out[0] = a * BATCH_INV;
}

extern "C" void kernel_launch(void* const* d_in, const int* in_sizes, int n_in,
                              void* d_out, int out_size, void* d_ws, size_t ws_size,
                              hipStream_t stream)
{
    const float* pred = (const float*)d_in[0];
    float*       out  = (float*)d_out;
    float*       ws   = (float*)d_ws;

    const int n_rows = in_sizes[0] / FEAT;                              // 131072
    const int grid   = (n_rows + ROWS_PER_BLOCK - 1) / ROWS_PER_BLOCK;  // 1024

    if (ws_size >= (size_t)grid * sizeof(float) && (grid % 4) == 0) {
        bpsl_main<false><<<grid, NTHREADS, 0, stream>>>(pred, n_rows, ws);
        bpsl_finish<<<1, 64, 0, stream>>>(ws, grid / 4, out);
    } else {
        (void)hipMemsetAsync(out, 0, sizeof(float), stream);
        bpsl_main<true><<<grid, NTHREADS, 0, stream>>>(pred, n_rows, out);
    }
}